// Round 2
// baseline (91.980 us; speedup 1.0000x reference)
//
#include <hip/hip_runtime.h>
#include <hip/hip_bf16.h>

#define BB 2
#define CC 8
#define NN 6400   // 80*80

// K1: per-pixel scalar projections f1,f2,f3 (Cr==1)
__global__ void proj_kernel(const float* __restrict__ x,
                            const float* __restrict__ w1, const float* __restrict__ b1,
                            const float* __restrict__ w2, const float* __restrict__ b2,
                            const float* __restrict__ w3, const float* __restrict__ b3,
                            float* __restrict__ f1, float* __restrict__ f2, float* __restrict__ f3) {
    int i = blockIdx.x * blockDim.x + threadIdx.x;
    if (i >= BB * NN) return;
    int b = i / NN;
    int n = i - b * NN;
    const float* xp = x + (size_t)b * CC * NN + n;
    float a1 = b1[0];
    float a2 = b2[0];
    float a3 = b3[0];
#pragma unroll
    for (int c = 0; c < CC; ++c) {
        float xv = xp[(size_t)c * NN];
        a1 = fmaf(xv, w1[c], a1);
        a2 = fmaf(xv, w2[c], a2);
        a3 = fmaf(xv, w3[c], a3);
    }
    f1[i] = a1;
    f2[i] = a2;
    f3[i] = a3;
}

// K2: partial softmax-weighted sums over an n-chunk.
// grid: (NN/256 m-tiles, nchunk, BB); 256 threads; each thread owns one m.
__global__ void attn_kernel(const float* __restrict__ f1, const float* __restrict__ f2,
                            const float* __restrict__ f3,
                            float* __restrict__ pnum, float* __restrict__ pden,
                            int chunkLen) {
    extern __shared__ float sm[];
    float* s1 = sm;              // chunkLen
    float* s3 = sm + chunkLen;   // chunkLen
    const int b  = blockIdx.z;
    const int ch = blockIdx.y;
    const int m  = blockIdx.x * blockDim.x + threadIdx.x;
    const int base = b * NN + ch * chunkLen;
    for (int j = threadIdx.x; j < chunkLen; j += blockDim.x) {
        s1[j] = f1[base + j];
        s3[j] = f3[base + j];
    }
    __syncthreads();
    if (m >= NN) return;
    // scores over n: f2[m] * f1[n]; fold log2(e) so the exp is a single v_exp_f32
    const float s = f2[b * NN + m] * 1.4426950408889634f;
    float num = 0.f, den = 0.f;
#pragma unroll 4
    for (int j = 0; j < chunkLen; ++j) {
        float e = __builtin_amdgcn_exp2f(s * s1[j]);  // LDS reads are uniform -> broadcast, conflict-free
        num = fmaf(s3[j], e, num);
        den += e;
    }
    const size_t o = (size_t)(ch * BB + b) * NN + m;  // [chunk][b][m]
    pnum[o] = num;
    pden[o] = den;
}

// K3: reduce partials, sigmoid gate, scale all C channels of x.
__global__ void finish_kernel(const float* __restrict__ x,
                              const float* __restrict__ pnum, const float* __restrict__ pden,
                              float* __restrict__ out, int nchunk) {
    int i = blockIdx.x * blockDim.x + threadIdx.x;
    if (i >= BB * NN) return;
    int b = i / NN;
    int m = i - b * NN;
    float num = 0.f, den = 0.f;
    for (int ch = 0; ch < nchunk; ++ch) {
        size_t o = (size_t)(ch * BB + b) * NN + m;
        num += pnum[o];
        den += pden[o];
    }
    float g = num / den;
    float sig = 1.0f / (1.0f + __builtin_amdgcn_exp2f(-g * 1.4426950408889634f));
    const float* xp = x + (size_t)b * CC * NN + m;
    float* op = out + (size_t)b * CC * NN + m;
#pragma unroll
    for (int c = 0; c < CC; ++c) {
        op[(size_t)c * NN] = xp[(size_t)c * NN] * sig;
    }
}

extern "C" void kernel_launch(void* const* d_in, const int* in_sizes, int n_in,
                              void* d_out, int out_size, void* d_ws, size_t ws_size,
                              hipStream_t stream) {
    const float* x  = (const float*)d_in[0];
    const float* w1 = (const float*)d_in[1];
    const float* b1 = (const float*)d_in[2];
    const float* w2 = (const float*)d_in[3];
    const float* b2 = (const float*)d_in[4];
    const float* w3 = (const float*)d_in[5];
    const float* b3 = (const float*)d_in[6];
    float* out = (float*)d_out;

    float* ws = (float*)d_ws;
    const size_t BN = (size_t)BB * NN;

    // pick nchunk (n-split for parallelism) that fits the workspace
    int nchunk = 8;
    while (nchunk > 1 && (size_t)(3 + 2 * nchunk) * BN * sizeof(float) > ws_size) nchunk >>= 1;

    float* f1   = ws;
    float* f2   = ws + BN;
    float* f3   = ws + 2 * BN;
    float* pnum = ws + 3 * BN;
    float* pden = pnum + (size_t)nchunk * BN;

    const int threads = 256;
    const int blocksBN = (int)((BN + threads - 1) / threads);

    proj_kernel<<<blocksBN, threads, 0, stream>>>(x, w1, b1, w2, b2, w3, b3, f1, f2, f3);

    const int chunkLen = NN / nchunk;
    dim3 g2(NN / threads, nchunk, BB);
    attn_kernel<<<g2, threads, 2 * chunkLen * sizeof(float), stream>>>(f1, f2, f3, pnum, pden, chunkLen);

    finish_kernel<<<blocksBN, threads, 0, stream>>>(x, pnum, pden, out, nchunk);
}

// Round 3
// 90.269 us; speedup vs baseline: 1.0190x; 1.0190x over previous
//
#include <hip/hip_runtime.h>
#include <hip/hip_bf16.h>

#define BB 2
#define CC 8
#define NN 6400     // 80*80
#define NCH 64      // n-chunks
#define CHLEN 100   // NN/NCH
#define THR 320     // threads/block (5 waves)
#define MPT 4       // m per thread
#define MT (THR*MPT) // 1280 m per block; 5 m-tiles exactly
#define LOG2E 1.4426950408889634f

// Fused: per-block recompute of f1/f3 (chunk) and f2 (own m's), then partial
// softmax-weighted sums over the n-chunk. grid (5 mtiles, NCH, BB).
__global__ __launch_bounds__(THR) void attn_fused(
    const float* __restrict__ x,
    const float* __restrict__ w1, const float* __restrict__ b1,
    const float* __restrict__ w2, const float* __restrict__ b2,
    const float* __restrict__ w3, const float* __restrict__ b3,
    float* __restrict__ pnum, float* __restrict__ pden) {
    __shared__ float4 s1v[CHLEN / 4];
    __shared__ float4 s3v[CHLEN / 4];
    const int b   = blockIdx.z;
    const int ch  = blockIdx.y;
    const int mt  = blockIdx.x;
    const int tid = threadIdx.x;
    const float* xb = x + (size_t)b * CC * NN;

    // Phase A1: chunk f1,f3 -> LDS (threads 0..99), pre-scaled by log2(e) on f1
    if (tid < CHLEN) {
        const int n = ch * CHLEN + tid;
        float a1 = b1[0], a3 = b3[0];
#pragma unroll
        for (int c = 0; c < CC; ++c) {
            float xv = xb[c * NN + n];
            a1 = fmaf(xv, w1[c], a1);
            a3 = fmaf(xv, w3[c], a3);
        }
        ((float*)s1v)[tid] = a1 * LOG2E;   // fold log2e here
        ((float*)s3v)[tid] = a3;
    }

    // Phase A2: own f2 for MPT m's (all threads), raw (log2e already folded)
    const int m0 = mt * MT + tid * MPT;
    float sc[MPT];
    {
        float bb2 = b2[0];
#pragma unroll
        for (int i = 0; i < MPT; ++i) sc[i] = bb2;
#pragma unroll
        for (int c = 0; c < CC; ++c) {
            const float wc = w2[c];
            const float4 xq = *(const float4*)(xb + (size_t)c * NN + m0);
            sc[0] = fmaf(xq.x, wc, sc[0]);
            sc[1] = fmaf(xq.y, wc, sc[1]);
            sc[2] = fmaf(xq.z, wc, sc[2]);
            sc[3] = fmaf(xq.w, wc, sc[3]);
        }
    }
    __syncthreads();

    // Phase B: partial num/den over the chunk
    float num[MPT] = {0.f, 0.f, 0.f, 0.f};
    float den[MPT] = {0.f, 0.f, 0.f, 0.f};
#pragma unroll 5
    for (int jj = 0; jj < CHLEN / 4; ++jj) {
        const float4 v1 = s1v[jj];   // uniform -> LDS broadcast, conflict-free
        const float4 v3 = s3v[jj];
        const float e1a[4] = {v1.x, v1.y, v1.z, v1.w};
        const float e3a[4] = {v3.x, v3.y, v3.z, v3.w};
#pragma unroll
        for (int k = 0; k < 4; ++k) {
            const float f1k = e1a[k];
            const float f3k = e3a[k];
#pragma unroll
            for (int i = 0; i < MPT; ++i) {
                const float e = __builtin_amdgcn_exp2f(sc[i] * f1k);
                num[i] = fmaf(f3k, e, num[i]);
                den[i] += e;
            }
        }
    }

    const size_t o = (size_t)(ch * BB + b) * NN + m0;
    *(float4*)(pnum + o) = make_float4(num[0], num[1], num[2], num[3]);
    *(float4*)(pden + o) = make_float4(den[0], den[1], den[2], den[3]);
}

// Reduce partials, sigmoid gate, scale all C channels of x. 4 m's per thread.
__global__ __launch_bounds__(64) void finish_kernel(
    const float* __restrict__ x,
    const float* __restrict__ pnum, const float* __restrict__ pden,
    float* __restrict__ out) {
    const int t  = blockIdx.x * blockDim.x + threadIdx.x;  // 0..BB*NN/4-1
    const int bm = t * 4;
    const int b  = bm / NN;
    const int m0 = bm - b * NN;
    float num[4] = {0.f, 0.f, 0.f, 0.f};
    float den[4] = {0.f, 0.f, 0.f, 0.f};
#pragma unroll 8
    for (int ch = 0; ch < NCH; ++ch) {
        const size_t o = (size_t)(ch * BB + b) * NN + m0;
        const float4 a = *(const float4*)(pnum + o);
        const float4 d = *(const float4*)(pden + o);
        num[0] += a.x; num[1] += a.y; num[2] += a.z; num[3] += a.w;
        den[0] += d.x; den[1] += d.y; den[2] += d.z; den[3] += d.w;
    }
    float sig[4];
#pragma unroll
    for (int i = 0; i < 4; ++i) {
        const float g = num[i] / den[i];
        sig[i] = 1.0f / (1.0f + __builtin_amdgcn_exp2f(-g * LOG2E));
    }
    const float* xb = x + (size_t)b * CC * NN + m0;
    float* ob = out + (size_t)b * CC * NN + m0;
#pragma unroll
    for (int c = 0; c < CC; ++c) {
        const float4 xq = *(const float4*)(xb + (size_t)c * NN);
        *(float4*)(ob + (size_t)c * NN) =
            make_float4(xq.x * sig[0], xq.y * sig[1], xq.z * sig[2], xq.w * sig[3]);
    }
}

extern "C" void kernel_launch(void* const* d_in, const int* in_sizes, int n_in,
                              void* d_out, int out_size, void* d_ws, size_t ws_size,
                              hipStream_t stream) {
    const float* x  = (const float*)d_in[0];
    const float* w1 = (const float*)d_in[1];
    const float* b1 = (const float*)d_in[2];
    const float* w2 = (const float*)d_in[3];
    const float* b2 = (const float*)d_in[4];
    const float* w3 = (const float*)d_in[5];
    const float* b3 = (const float*)d_in[6];
    float* out = (float*)d_out;

    float* ws = (float*)d_ws;
    const size_t BN = (size_t)BB * NN;
    float* pnum = ws;
    float* pden = ws + (size_t)NCH * BN;

    dim3 g2(NN / MT, NCH, BB);  // (5, 64, 2)
    attn_fused<<<g2, THR, 0, stream>>>(x, w1, b1, w2, b2, w3, b3, pnum, pden);

    finish_kernel<<<(int)(BN / 4 / 64), 64, 0, stream>>>(x, pnum, pden, out);
}

// Round 5
// 87.619 us; speedup vs baseline: 1.0498x; 1.0303x over previous
//
#include <hip/hip_runtime.h>
#include <hip/hip_bf16.h>

#define BB 2
#define CC 8
#define NN 6400     // 80*80
#define NCH 64      // n-chunks
#define CHLEN 100   // NN/NCH
#define THR 320     // threads/block (5 waves)
#define MPT 4       // m per thread
#define MT (THR*MPT) // 1280 m per block; 5 m-tiles exactly
#define LOG2E 1.4426950408889634f

typedef float v2f __attribute__((ext_vector_type(2)));

// Fused proj + partial softmax sums per (m-tile, n-chunk, b).
// grid (5, NCH, BB) = 640 blocks; 3200 waves (~3.1/SIMD).
__global__ __launch_bounds__(THR) void attn_fused(
    const float* __restrict__ x,
    const float* __restrict__ w1, const float* __restrict__ b1,
    const float* __restrict__ w2, const float* __restrict__ b2,
    const float* __restrict__ w3, const float* __restrict__ b3,
    float* __restrict__ pnum, float* __restrict__ pden) {
    __shared__ float4 s1v[CHLEN / 4];
    __shared__ float4 s3v[CHLEN / 4];
    const int b   = blockIdx.z;
    const int ch  = blockIdx.y;
    const int mt  = blockIdx.x;
    const int tid = threadIdx.x;
    const float* xb = x + (size_t)b * CC * NN;

    // Phase A1: chunk f1,f3 -> LDS (threads 0..99); fold log2(e) into f1
    if (tid < CHLEN) {
        const int n = ch * CHLEN + tid;
        float a1 = b1[0], a3 = b3[0];
#pragma unroll
        for (int c = 0; c < CC; ++c) {
            float xv = xb[c * NN + n];
            a1 = fmaf(xv, w1[c], a1);
            a3 = fmaf(xv, w3[c], a3);
        }
        ((float*)s1v)[tid] = a1 * LOG2E;
        ((float*)s3v)[tid] = a3;
    }

    // Phase A2: own f2 for MPT m's (all threads)
    const int m0 = mt * MT + tid * MPT;
    float sc[MPT];
    {
        float bb2 = b2[0];
#pragma unroll
        for (int i = 0; i < MPT; ++i) sc[i] = bb2;
#pragma unroll
        for (int c = 0; c < CC; ++c) {
            const float wc = w2[c];
            const float4 xq = *(const float4*)(xb + (size_t)c * NN + m0);
            sc[0] = fmaf(xq.x, wc, sc[0]);
            sc[1] = fmaf(xq.y, wc, sc[1]);
            sc[2] = fmaf(xq.z, wc, sc[2]);
            sc[3] = fmaf(xq.w, wc, sc[3]);
        }
    }
    __syncthreads();

    // Phase B: packed (num,den) accumulators -> v_pk_fma_f32 / v_pk_mul_f32.
    // Per exp: 0.5 pk_mul + 1 pk_fma instead of mul+fma+add.
    v2f acc[MPT];
#pragma unroll
    for (int i = 0; i < MPT; ++i) acc[i] = (v2f){0.f, 0.f};
    v2f sc01 = (v2f){sc[0], sc[1]};
    v2f sc23 = (v2f){sc[2], sc[3]};
#pragma unroll 5
    for (int jj = 0; jj < CHLEN / 4; ++jj) {
        const float4 v1 = s1v[jj];   // uniform address -> LDS broadcast
        const float4 v3 = s3v[jj];
        const float e1a[4] = {v1.x, v1.y, v1.z, v1.w};
        const float e3a[4] = {v3.x, v3.y, v3.z, v3.w};
#pragma unroll
        for (int k = 0; k < 4; ++k) {
            const float f1k = e1a[k];
            const v2f  f1k2 = (v2f){f1k, f1k};
            const v2f  w    = (v2f){e3a[k], 1.0f};
            const v2f  t01  = sc01 * f1k2;   // v_pk_mul_f32
            const v2f  t23  = sc23 * f1k2;
            const float e0 = __builtin_amdgcn_exp2f(t01.x);
            const float e1 = __builtin_amdgcn_exp2f(t01.y);
            const float e2 = __builtin_amdgcn_exp2f(t23.x);
            const float e3 = __builtin_amdgcn_exp2f(t23.y);
            acc[0] = __builtin_elementwise_fma((v2f){e0, e0}, w, acc[0]);
            acc[1] = __builtin_elementwise_fma((v2f){e1, e1}, w, acc[1]);
            acc[2] = __builtin_elementwise_fma((v2f){e2, e2}, w, acc[2]);
            acc[3] = __builtin_elementwise_fma((v2f){e3, e3}, w, acc[3]);
        }
    }

    const size_t o = (size_t)(ch * BB + b) * NN + m0;
    *(float4*)(pnum + o) = make_float4(acc[0].x, acc[1].x, acc[2].x, acc[3].x);
    *(float4*)(pden + o) = make_float4(acc[0].y, acc[1].y, acc[2].y, acc[3].y);
}

// Reduce partials, sigmoid gate, scale all C channels of x. 4 m's per thread.
__global__ __launch_bounds__(64) void finish_kernel(
    const float* __restrict__ x,
    const float* __restrict__ pnum, const float* __restrict__ pden,
    float* __restrict__ out) {
    const int t  = blockIdx.x * blockDim.x + threadIdx.x;  // 0..BB*NN/4-1
    const int bm = t * 4;
    const int b  = bm / NN;
    const int m0 = bm - b * NN;
    float num[4] = {0.f, 0.f, 0.f, 0.f};
    float den[4] = {0.f, 0.f, 0.f, 0.f};
#pragma unroll 8
    for (int ch = 0; ch < NCH; ++ch) {
        const size_t o = (size_t)(ch * BB + b) * NN + m0;
        const float4 a = *(const float4*)(pnum + o);
        const float4 d = *(const float4*)(pden + o);
        num[0] += a.x; num[1] += a.y; num[2] += a.z; num[3] += a.w;
        den[0] += d.x; den[1] += d.y; den[2] += d.z; den[3] += d.w;
    }
    float sig[4];
#pragma unroll
    for (int i = 0; i < 4; ++i) {
        const float g = num[i] / den[i];
        sig[i] = 1.0f / (1.0f + __builtin_amdgcn_exp2f(-g * LOG2E));
    }
    const float* xp = x + (size_t)b * CC * NN + m0;
    float* op = out + (size_t)b * CC * NN + m0;
#pragma unroll
    for (int c = 0; c < CC; ++c) {
        const float4 xq = *(const float4*)(xp + (size_t)c * NN);
        *(float4*)(op + (size_t)c * NN) =
            make_float4(xq.x * sig[0], xq.y * sig[1], xq.z * sig[2], xq.w * sig[3]);
    }
}

extern "C" void kernel_launch(void* const* d_in, const int* in_sizes, int n_in,
                              void* d_out, int out_size, void* d_ws, size_t ws_size,
                              hipStream_t stream) {
    const float* x  = (const float*)d_in[0];
    const float* w1 = (const float*)d_in[1];
    const float* b1 = (const float*)d_in[2];
    const float* w2 = (const float*)d_in[3];
    const float* b2 = (const float*)d_in[4];
    const float* w3 = (const float*)d_in[5];
    const float* b3 = (const float*)d_in[6];
    float* out = (float*)d_out;

    float* ws = (float*)d_ws;
    const size_t BN = (size_t)BB * NN;
    float* pnum = ws;
    float* pden = ws + (size_t)NCH * BN;

    dim3 g2(NN / MT, NCH, BB);  // (5, 64, 2)
    attn_fused<<<g2, THR, 0, stream>>>(x, w1, b1, w2, b2, w3, b3, pnum, pden);

    finish_kernel<<<(int)(BN / 4 / 64), 64, 0, stream>>>(x, pnum, pden, out);
}